// Round 4
// baseline (242.166 us; speedup 1.0000x reference)
//
#include <hip/hip_runtime.h>

// SkeLossMultiClass: fused single-pass streaming reduction.
// B=2, C=4, D=64, H=256, W=256; classes 1..3; BETA=25, EPS=1e-4.
// Per element, per class c: ev=(v==c), es=(s==c)
//   num_c  += p_c * ev * (0.1+es)
//   den1_c += p_c * (1.1 - ev + es)
//   den2_c += ev * (0.1+es)
// score = (26*num+eps)/(den1+25*den2+eps); loss = -mean_b(sum_c score/3)
// Channel 0 of probs never read (33 MB saved). Ignore-mask is a provable no-op.
// Last-finishing block (device-scope counter) does the 72 KB finalize reduce
// in a fixed order -> deterministic output, no second kernel launch.

#define DHW (64 * 256 * 256)   // 4194304
#define NVEC (DHW / 4)         // 1048576 float4/int4 per (b,c)
#define GX 1024
#define TPB 256
#define NITER 4
#define CHUNK (TPB * NITER)    // 1024 float4s: contiguous 16 KB per stream/block
#define NACC 9                 // num[3], den1[3], den2[3]
#define TOTAL_BLOCKS (GX * 2)

__global__ __launch_bounds__(TPB) void ske_fused_kernel(
    const float* __restrict__ out, const int* __restrict__ labels,
    float* __restrict__ ws, unsigned* __restrict__ ctr,
    float* __restrict__ res)
{
    const int b = blockIdx.y;
    const int bx = blockIdx.x;
    const float4* p1 = (const float4*)(out + ((size_t)(b * 4 + 1)) * DHW);
    const float4* p2 = (const float4*)(out + ((size_t)(b * 4 + 2)) * DHW);
    const float4* p3 = (const float4*)(out + ((size_t)(b * 4 + 3)) * DHW);
    const int4* ves = (const int4*)(labels + (size_t)(b * 2) * DHW);
    const int4* ske = ves + NVEC;

    // Contiguous 16 KB chunk per stream per block: 4 KB per wave-load,
    // consecutive q hit adjacent pages -> DRAM row locality.
    const int base = bx * CHUNK + threadIdx.x;

    float4 A1[NITER], A2[NITER], A3[NITER];
    int4 V[NITER], S[NITER];
#pragma unroll
    for (int q = 0; q < NITER; ++q) {
        const int i = base + q * TPB;
        A1[q] = p1[i];
        A2[q] = p2[i];
        A3[q] = p3[i];
        V[q] = ves[i];
        S[q] = ske[i];
    }

    float num[3] = {0.f, 0.f, 0.f};
    float d1[3]  = {0.f, 0.f, 0.f};
    float d2[3]  = {0.f, 0.f, 0.f};

#pragma unroll
    for (int q = 0; q < NITER; ++q) {
        const float pv[4][3] = {{A1[q].x, A2[q].x, A3[q].x},
                                {A1[q].y, A2[q].y, A3[q].y},
                                {A1[q].z, A2[q].z, A3[q].z},
                                {A1[q].w, A2[q].w, A3[q].w}};
        const int vv[4] = {V[q].x, V[q].y, V[q].z, V[q].w};
        const int sv[4] = {S[q].x, S[q].y, S[q].z, S[q].w};
#pragma unroll
        for (int j = 0; j < 4; ++j) {
#pragma unroll
            for (int c = 0; c < 3; ++c) {
                const bool mv = (vv[j] == c + 1);
                const bool ms = (sv[j] == c + 1);
                const float t   = ms ? 1.1f : 0.1f;      // 0.1 + es
                const float w   = mv ? t : 0.0f;         // ev*(0.1+es)
                const float imp = mv ? t : (t + 1.0f);   // 1.1 - ev + es
                num[c] += pv[j][c] * w;
                d1[c]  += pv[j][c] * imp;
                d2[c]  += w;
            }
        }
    }

    // wave (64-lane) shuffle reduce, cross-wave via LDS, per-block slot write
    __shared__ float red[4][NACC];
    const int lane = threadIdx.x & 63;
    const int wid = threadIdx.x >> 6;
    float acc[NACC];
#pragma unroll
    for (int k = 0; k < 3; ++k) { acc[k] = num[k]; acc[3 + k] = d1[k]; acc[6 + k] = d2[k]; }
#pragma unroll
    for (int k = 0; k < NACC; ++k) {
        float v = acc[k];
#pragma unroll
        for (int off = 32; off > 0; off >>= 1) v += __shfl_down(v, off, 64);
        if (lane == 0) red[wid][k] = v;
    }
    __syncthreads();
    if (wid == 0 && lane < NACC) {
        const float v = red[0][lane] + red[1][lane] + red[2][lane] + red[3][lane];
        ws[((size_t)(b * NACC + lane)) * GX + bx] = v;
    }

    // --- last-block finalize (release: fence before counter bump) ---
    __threadfence();                      // agent-scope: slot stores visible
    __shared__ unsigned done;
    if (threadIdx.x == 0) done = atomicAdd(ctr, 1u);
    __syncthreads();
    if (done != TOTAL_BLOCKS - 1) return;

    __threadfence();                      // acquire: see all other blocks' slots
    // 18 rows x GX floats; thread t reads float4 #t of each row (GX==TPB*4).
    float facc[2 * NACC];
#pragma unroll
    for (int s = 0; s < 2 * NACC; ++s) {
        const float4 v = ((const float4*)(ws + (size_t)s * GX))[threadIdx.x];
        facc[s] = (v.x + v.y) + (v.z + v.w);
    }
    __shared__ float red2[4][2 * NACC];
#pragma unroll
    for (int s = 0; s < 2 * NACC; ++s) {
        float v = facc[s];
#pragma unroll
        for (int off = 32; off > 0; off >>= 1) v += __shfl_down(v, off, 64);
        if (lane == 0) red2[wid][s] = v;
    }
    __syncthreads();
    if (threadIdx.x == 0) {
        float tot[2 * NACC];
#pragma unroll
        for (int s = 0; s < 2 * NACC; ++s)
            tot[s] = red2[0][s] + red2[1][s] + red2[2][s] + red2[3][s];
        float loss = 0.f;
#pragma unroll
        for (int bb = 0; bb < 2; ++bb) {
            float ssum = 0.f;
#pragma unroll
            for (int c = 0; c < 3; ++c) {
                const float n  = tot[bb * NACC + c];
                const float e1 = tot[bb * NACC + 3 + c];
                const float e2 = tot[bb * NACC + 6 + c];
                ssum += (26.f * n + 1e-4f) / (e1 + 25.f * e2 + 1e-4f);
            }
            loss += ssum * (1.f / 3.f);
        }
        res[0] = -loss * 0.5f;
    }
}

extern "C" void kernel_launch(void* const* d_in, const int* in_sizes, int n_in,
                              void* d_out, int out_size, void* d_ws, size_t ws_size,
                              hipStream_t stream) {
    const float* out_probs = (const float*)d_in[0];
    const int* labels = (const int*)d_in[1];
    float* ws = (float*)d_ws;
    unsigned* ctr = (unsigned*)(ws + 2 * NACC * GX);

    // ws is poisoned once (0xAA), never re-poisoned: counter must be zeroed
    // every call (4-byte memset node; graph-capture-safe, proven in R0).
    hipMemsetAsync(ctr, 0, sizeof(unsigned), stream);

    dim3 grid(GX, 2);
    ske_fused_kernel<<<grid, TPB, 0, stream>>>(out_probs, labels, ws, ctr,
                                               (float*)d_out);
}

// Round 5
// 36.744 us; speedup vs baseline: 6.5906x; 6.5906x over previous
//
#include <hip/hip_runtime.h>

// SkeLossMultiClass: streaming reduction, two kernels (partial + final).
// B=2, C=4, D=64, H=256, W=256; classes 1..3; BETA=25, EPS=1e-4.
// Per element, per class c: ev=(v==c), es=(s==c)
//   num_c  += p_c * ev * (0.1+es)
//   den1_c += p_c * (1.1 - ev + es)
//   den2_c += ev * (0.1+es)
// score = (26*num+eps)/(den1+25*den2+eps); loss = -mean_b(sum_c score/3)
// Channel 0 of probs never read (33 MB saved). Ignore-mask is a provable no-op.
// NOTE (R4 lesson): NO __threadfence() on the hot path — per-thread agent-scope
// fences emit L2 writeback ops and serialized the whole chip (40.9 -> 242 us).

#define DHW (64 * 256 * 256)   // 4194304
#define NVEC (DHW / 4)         // 1048576 float4/int4 per (b,c)
#define GX 1024
#define TPB 256
#define NITER 4
#define CHUNK (TPB * NITER)    // 1024 float4s: contiguous 16 KB per stream/block
#define NACC 9                 // num[3], den1[3], den2[3]

__global__ __launch_bounds__(TPB) void ske_partial_kernel(
    const float* __restrict__ out, const int* __restrict__ labels,
    float* __restrict__ ws)
{
    const int b = blockIdx.y;
    const int bx = blockIdx.x;
    const float4* p1 = (const float4*)(out + ((size_t)(b * 4 + 1)) * DHW);
    const float4* p2 = (const float4*)(out + ((size_t)(b * 4 + 2)) * DHW);
    const float4* p3 = (const float4*)(out + ((size_t)(b * 4 + 3)) * DHW);
    const int4* ves = (const int4*)(labels + (size_t)(b * 2) * DHW);
    const int4* ske = ves + NVEC;

    // Contiguous 16 KB per stream per block (DRAM row locality); 20 independent
    // loads issued up-front, one wait.
    const int base = bx * CHUNK + threadIdx.x;

    float4 A1[NITER], A2[NITER], A3[NITER];
    int4 V[NITER], S[NITER];
#pragma unroll
    for (int q = 0; q < NITER; ++q) {
        const int i = base + q * TPB;
        A1[q] = p1[i];
        A2[q] = p2[i];
        A3[q] = p3[i];
        V[q] = ves[i];
        S[q] = ske[i];
    }

    float num[3] = {0.f, 0.f, 0.f};
    float d1[3]  = {0.f, 0.f, 0.f};
    float d2[3]  = {0.f, 0.f, 0.f};

#pragma unroll
    for (int q = 0; q < NITER; ++q) {
        const float pv[4][3] = {{A1[q].x, A2[q].x, A3[q].x},
                                {A1[q].y, A2[q].y, A3[q].y},
                                {A1[q].z, A2[q].z, A3[q].z},
                                {A1[q].w, A2[q].w, A3[q].w}};
        const int vv[4] = {V[q].x, V[q].y, V[q].z, V[q].w};
        const int sv[4] = {S[q].x, S[q].y, S[q].z, S[q].w};
#pragma unroll
        for (int j = 0; j < 4; ++j) {
#pragma unroll
            for (int c = 0; c < 3; ++c) {
                const bool mv = (vv[j] == c + 1);
                const bool ms = (sv[j] == c + 1);
                const float t   = ms ? 1.1f : 0.1f;      // 0.1 + es
                const float w   = mv ? t : 0.0f;         // ev*(0.1+es)
                const float imp = mv ? t : (t + 1.0f);   // 1.1 - ev + es
                num[c] += pv[j][c] * w;
                d1[c]  += pv[j][c] * imp;
                d2[c]  += w;
            }
        }
    }

    // wave (64-lane) shuffle reduce, cross-wave via LDS, per-block slot write
    __shared__ float red[4][NACC];
    const int lane = threadIdx.x & 63;
    const int wid = threadIdx.x >> 6;
    float acc[NACC];
#pragma unroll
    for (int k = 0; k < 3; ++k) { acc[k] = num[k]; acc[3 + k] = d1[k]; acc[6 + k] = d2[k]; }
#pragma unroll
    for (int k = 0; k < NACC; ++k) {
        float v = acc[k];
#pragma unroll
        for (int off = 32; off > 0; off >>= 1) v += __shfl_down(v, off, 64);
        if (lane == 0) red[wid][k] = v;
    }
    __syncthreads();
    if (wid == 0 && lane < NACC) {
        const float v = red[0][lane] + red[1][lane] + red[2][lane] + red[3][lane];
        // slot layout: ws[(b*NACC + k) * GX + bx] -> every slot written every call
        ws[((size_t)(b * NACC + lane)) * GX + bx] = v;
    }
}

__global__ __launch_bounds__(TPB) void ske_final_kernel(
    const float* __restrict__ ws, float* __restrict__ out)
{
    // 18 rows x GX floats; thread t reads float4 #t of each row (GX==TPB*4):
    // 18 independent vec loads, one wait, 18 parallel shuffle-reduces.
    float acc[2 * NACC];
#pragma unroll
    for (int s = 0; s < 2 * NACC; ++s) {
        const float4 v = ((const float4*)(ws + (size_t)s * GX))[threadIdx.x];
        acc[s] = (v.x + v.y) + (v.z + v.w);
    }
    __shared__ float red[4][2 * NACC];
    const int lane = threadIdx.x & 63;
    const int wid = threadIdx.x >> 6;
#pragma unroll
    for (int s = 0; s < 2 * NACC; ++s) {
        float v = acc[s];
#pragma unroll
        for (int off = 32; off > 0; off >>= 1) v += __shfl_down(v, off, 64);
        if (lane == 0) red[wid][s] = v;
    }
    __syncthreads();
    if (threadIdx.x == 0) {
        float tot[2 * NACC];
#pragma unroll
        for (int s = 0; s < 2 * NACC; ++s)
            tot[s] = red[0][s] + red[1][s] + red[2][s] + red[3][s];
        float loss = 0.f;
#pragma unroll
        for (int b = 0; b < 2; ++b) {
            float ssum = 0.f;
#pragma unroll
            for (int c = 0; c < 3; ++c) {
                const float n  = tot[b * NACC + c];
                const float e1 = tot[b * NACC + 3 + c];
                const float e2 = tot[b * NACC + 6 + c];
                ssum += (26.f * n + 1e-4f) / (e1 + 25.f * e2 + 1e-4f);
            }
            loss += ssum * (1.f / 3.f);
        }
        out[0] = -loss * 0.5f;
    }
}

extern "C" void kernel_launch(void* const* d_in, const int* in_sizes, int n_in,
                              void* d_out, int out_size, void* d_ws, size_t ws_size,
                              hipStream_t stream) {
    const float* out_probs = (const float*)d_in[0];
    const int* labels = (const int*)d_in[1];
    float* ws = (float*)d_ws;

    dim3 grid(GX, 2);
    ske_partial_kernel<<<grid, TPB, 0, stream>>>(out_probs, labels, ws);
    ske_final_kernel<<<1, TPB, 0, stream>>>(ws, (float*)d_out);
}